// Round 6
// baseline (191.767 us; speedup 1.0000x reference)
//
#include <hip/hip_runtime.h>
#include <hip/hip_bf16.h>

// Problem: B=256, A=128, F=512, D=6, C=512
// out[b,a,:] = (atoms[b,a,:] + sum_j atoms[b,bonds[b,a,j],:]) @ W[deg] + bias[deg]
// deg = count(bonds != -1), in 0..5.
//
// R6: double-buffered gemm K-loop (one barrier/iter, gather latency hidden
// behind MFMA), XOR-swizzled LDS (16-way -> 2-way conflicts), prep fused
// into a single kernel (transpose + bucket + neighbor-sum).

#define NB 256
#define NA 128
#define NF 512
#define ND 6
#define NC 512
#define NATOMS (NB * NA)   // 32768

typedef __attribute__((ext_vector_type(8))) short frag8;
typedef __attribute__((ext_vector_type(4))) float f32x4;

static __device__ inline unsigned short f2bu(float f) {
    __hip_bfloat16 h = __float2bfloat16(f);
    return *reinterpret_cast<unsigned short*>(&h);
}
static __device__ inline unsigned int pack2(float a, float b) {
    return (unsigned int)f2bu(a) | ((unsigned int)f2bu(b) << 16);
}
static __device__ inline void async16(const void* g, void* l) {
    __builtin_amdgcn_global_load_lds(
        (const __attribute__((address_space(1))) void*)g,
        (__attribute__((address_space(3))) void*)l, 16, 0, 0);
}

// ---------------- fused prep kernel ----------------
// blocks [0,1536):        W[d][f][c] f32 -> Wt[d][c][f] bf16 (tiled transpose)
// blocks [1536,1568):     degree bucketing (LDS-aggregated histogram)
// blocks [1568,1568+8192): neighbor sum -> summed bf16 (1 wave/atom)
#define PREP_T 1536
#define PREP_B (PREP_T + 32)
#define PREP_S (PREP_B + NATOMS / 4)

__global__ __launch_bounds__(256) void prep(
    const float* __restrict__ atoms, const int* __restrict__ bonds,
    const float* __restrict__ W, __hip_bfloat16* __restrict__ Wt,
    __hip_bfloat16* __restrict__ summed, int* __restrict__ counts,
    int* __restrict__ bucket) {
    const int blk = blockIdx.x;
    const int tid = threadIdx.x;

    if (blk < PREP_T) {
        // ---- transpose W tile 32x32 ----
        __shared__ float t[32][33];
        const int tx = tid & 31, ty = tid >> 5;           // (32,8)
        const int d   = blk >> 8;
        const int rem = blk & 255;
        const int c0  = (rem & 15) * 32;
        const int f0  = (rem >> 4) * 32;
        #pragma unroll
        for (int r = 0; r < 32; r += 8)
            t[ty + r][tx] = W[((size_t)(d * NF + f0 + ty + r)) * NC + c0 + tx];
        __syncthreads();
        #pragma unroll
        for (int r = 0; r < 32; r += 8)
            Wt[((size_t)(d * NC + c0 + ty + r)) * NF + f0 + tx] =
                __float2bfloat16(t[tx][ty + r]);
    } else if (blk < PREP_B) {
        // ---- bucket atoms by degree ----
        __shared__ int lcnt[ND];
        __shared__ int lbase[ND];
        const int b = blk - PREP_T;
        if (tid < ND) lcnt[tid] = 0;
        __syncthreads();
        int deg[4], loc[4], gg[4];
        #pragma unroll
        for (int i = 0; i < 4; ++i) {
            int g = b * 1024 + i * 256 + tid;
            gg[i] = g;
            int dg = 0;
            #pragma unroll
            for (int j = 0; j < ND; ++j) dg += (bonds[g * ND + j] >= 0);
            deg[i] = dg;
            loc[i] = atomicAdd(&lcnt[dg], 1);
        }
        __syncthreads();
        if (tid < ND) lbase[tid] = atomicAdd(&counts[tid], lcnt[tid]);
        __syncthreads();
        #pragma unroll
        for (int i = 0; i < 4; ++i)
            bucket[deg[i] * NATOMS + lbase[deg[i]] + loc[i]] = gg[i];
    } else {
        // ---- neighbor gather/sum: 1 wave/atom, lane covers 8 contiguous f32 ----
        const int wave = tid >> 6;
        const int lane = tid & 63;
        const int g    = (blk - PREP_B) * 4 + wave;
        const float4* a4 = (const float4*)atoms;   // row = 128 float4

        int   nb[ND];
        float msk[ND];
        #pragma unroll
        for (int j = 0; j < ND; ++j) {
            int n = bonds[g * ND + j];
            msk[j] = (n >= 0) ? 1.0f : 0.0f;
            nb[j]  = (n >= 0) ? n : 0;
        }
        const int rowbase = g & ~(NA - 1);

        float4 s0 = a4[(size_t)g * 128 + 2 * lane];
        float4 s1 = a4[(size_t)g * 128 + 2 * lane + 1];
        float4 v0[ND], v1[ND];
        #pragma unroll
        for (int j = 0; j < ND; ++j) {
            const size_t base = (size_t)(rowbase + nb[j]) * 128 + 2 * lane;
            v0[j] = a4[base];
            v1[j] = a4[base + 1];
        }
        #pragma unroll
        for (int j = 0; j < ND; ++j) {
            s0.x = fmaf(v0[j].x, msk[j], s0.x); s0.y = fmaf(v0[j].y, msk[j], s0.y);
            s0.z = fmaf(v0[j].z, msk[j], s0.z); s0.w = fmaf(v0[j].w, msk[j], s0.w);
            s1.x = fmaf(v1[j].x, msk[j], s1.x); s1.y = fmaf(v1[j].y, msk[j], s1.y);
            s1.z = fmaf(v1[j].z, msk[j], s1.z); s1.w = fmaf(v1[j].w, msk[j], s1.w);
        }
        uint4 o;
        o.x = pack2(s0.x, s0.y); o.y = pack2(s0.z, s0.w);
        o.z = pack2(s1.x, s1.y); o.w = pack2(s1.z, s1.w);
        ((uint4*)summed)[(size_t)g * 64 + lane] = o;   // 8 bf16 at elem 8*lane
    }
}

// ---------------- gemm: per-degree gathered GEMM, double-buffered ----------------
// grid (24 = deg*col fast, 256 row-tiles slow); block 256 (4 waves, 2x2 of 64x64).
// BM=BN=128, BK=64. LDS layout XOR-swizzled: (row, slot) holds global 16B-seg
// (slot ^ (row&7)); staging fixes lane->slot, so the swizzle is applied on the
// global address; fragment reads un-swizzle -> 2-way bank conflicts (free).
__global__ __launch_bounds__(256, 2) void gemm_deg(
    const __hip_bfloat16* __restrict__ summed, const __hip_bfloat16* __restrict__ Wt,
    const float* __restrict__ bias, const int* __restrict__ counts,
    const int* __restrict__ bucket, float* __restrict__ out) {
    const int bx = blockIdx.x;          // 0..23
    const int d  = bx % ND;
    const int n0 = (bx / ND) * 128;
    const int Md = counts[d];
    const int m0 = blockIdx.y * 128;
    if (m0 >= Md) return;

    __shared__ __align__(16) __hip_bfloat16 sA[2][128 * 64];
    __shared__ __align__(16) __hip_bfloat16 sB[2][128 * 64];
    __shared__ int sRows[128];

    const int tid = threadIdx.x;
    if (tid < 128) {
        int r = m0 + tid;
        sRows[tid] = (r < Md) ? bucket[d * NATOMS + r] : -1;
    }
    __syncthreads();

    const int lane = tid & 63;
    const int w    = tid >> 6;
    const int srow = lane >> 3;                 // 0..7
    const int slot = lane & 7;                  // fixed LDS 16B slot
    const int sseg = slot ^ srow;               // global segment this lane fetches

    const char* smB = (const char*)summed;
    const char* wtB = (const char*)Wt + (size_t)(d * NC + n0) * (NF * 2);
    size_t gA[4];
    int    rowc[4];
    #pragma unroll
    for (int c = 0; c < 4; ++c) {
        rowc[c] = w * 32 + c * 8 + srow;
        int q = sRows[rowc[c]];
        gA[c] = (size_t)((q < 0) ? 0 : q) * (NF * 2);
    }

    const int quad = lane >> 4, l16 = lane & 15;
    const int wy = w >> 1, wx = w & 1;

    f32x4 acc[4][4];
    #pragma unroll
    for (int i = 0; i < 4; ++i)
        #pragma unroll
        for (int j = 0; j < 4; ++j) acc[i][j] = (f32x4)0.0f;

    // stage K-tile kt into buffer p (8 async16/thread)
    #define STAGE(kt, p)                                                        \
        {                                                                       \
            const int koff = (kt) * 128 + sseg * 16;                            \
            _Pragma("unroll")                                                   \
            for (int c = 0; c < 4; ++c) {                                       \
                async16(smB + gA[c] + koff, &sA[p][(w * 32 + c * 8) * 64]);     \
                async16(wtB + (size_t)rowc[c] * (NF * 2) + koff,                \
                        &sB[p][(w * 32 + c * 8) * 64]);                         \
            }                                                                   \
        }

    STAGE(0, 0)
    #pragma unroll
    for (int kt = 0; kt < 8; ++kt) {
        const int p = kt & 1;
        __syncthreads();                 // drains buf[p] loads (vmcnt0) + prior reads
        if (kt < 7) STAGE(kt + 1, 1 - p)
        #pragma unroll
        for (int ks = 0; ks < 2; ++ks) {
            frag8 aF[4], bF[4];
            #pragma unroll
            for (int i = 0; i < 4; ++i) {
                const int R = wy * 64 + i * 16 + l16;
                const int s = (quad + 4 * ks) ^ (R & 7);
                aF[i] = *(const frag8*)&sA[p][R * 64 + s * 8];
            }
            #pragma unroll
            for (int j = 0; j < 4; ++j) {
                const int R = wx * 64 + j * 16 + l16;
                const int s = (quad + 4 * ks) ^ (R & 7);
                bF[j] = *(const frag8*)&sB[p][R * 64 + s * 8];
            }
            #pragma unroll
            for (int i = 0; i < 4; ++i)
                #pragma unroll
                for (int j = 0; j < 4; ++j)
                    acc[i][j] = __builtin_amdgcn_mfma_f32_16x16x32_bf16(
                        aF[i], bF[j], acc[i][j], 0, 0, 0);
        }
    }
    #undef STAGE

    // epilogue: C/D layout col = lane&15, row = quad*4 + reg; output FLOAT32
    #pragma unroll
    for (int j = 0; j < 4; ++j) {
        const int n = n0 + wx * 64 + j * 16 + l16;
        const float bv = bias[d * NC + n];
        #pragma unroll
        for (int i = 0; i < 4; ++i) {
            #pragma unroll
            for (int r = 0; r < 4; ++r) {
                const int tr = wy * 64 + i * 16 + quad * 4 + r;
                const int g  = sRows[tr];
                if (g >= 0)
                    out[(size_t)g * NC + n] = acc[i][j][r] + bv;
            }
        }
    }
}

extern "C" void kernel_launch(void* const* d_in, const int* in_sizes, int n_in,
                              void* d_out, int out_size, void* d_ws, size_t ws_size,
                              hipStream_t stream) {
    const float* atoms = (const float*)d_in[0];
    const int*   bonds = (const int*)d_in[1];
    const float* W     = (const float*)d_in[2];
    const float* bias  = (const float*)d_in[3];
    float* out = (float*)d_out;

    // workspace layout
    char* ws = (char*)d_ws;
    int* counts = (int*)ws;                                   // 6 ints (zeroed)
    int* bucket = (int*)(ws + 1024);                          // 6*32768 ints
    __hip_bfloat16* Wt     = (__hip_bfloat16*)(ws + 1024 + 786432);            // 3 MB
    __hip_bfloat16* summed = (__hip_bfloat16*)(ws + 1024 + 786432 + 3145728);  // 32 MB

    hipMemsetAsync(counts, 0, 1024, stream);

    prep<<<PREP_S, 256, 0, stream>>>(atoms, bonds, W, Wt, summed, counts, bucket);

    gemm_deg<<<dim3(24, NATOMS / 128), 256, 0, stream>>>(
        summed, Wt, bias, counts, bucket, out);
}

// Round 7
// 184.361 us; speedup vs baseline: 1.0402x; 1.0402x over previous
//
#include <hip/hip_runtime.h>
#include <hip/hip_bf16.h>

// Problem: B=256, A=128, F=512, D=6, C=512
// out[b,a,:] = (atoms[b,a,:] + sum_j atoms[b,bonds[b,a,j],:]) @ W[deg] + bias[deg]
// deg = count(bonds != -1), in 0..5.
//
// R7: gemm K-loop double-buffered at BK=32 so total LDS stays ~33 KB ->
// 4 blocks/CU (R6's dbuf at BK=64 cost occupancy and regressed). XOR swizzle
// (seg ^ (row>>1)&3) keeps fragment reads at free 2-way conflicts.

#define NB 256
#define NA 128
#define NF 512
#define ND 6
#define NC 512
#define NATOMS (NB * NA)   // 32768

typedef __attribute__((ext_vector_type(8))) short frag8;
typedef __attribute__((ext_vector_type(4))) float f32x4;

static __device__ inline unsigned short f2bu(float f) {
    __hip_bfloat16 h = __float2bfloat16(f);
    return *reinterpret_cast<unsigned short*>(&h);
}
static __device__ inline unsigned int pack2(float a, float b) {
    return (unsigned int)f2bu(a) | ((unsigned int)f2bu(b) << 16);
}
static __device__ inline void async16(const void* g, void* l) {
    __builtin_amdgcn_global_load_lds(
        (const __attribute__((address_space(1))) void*)g,
        (__attribute__((address_space(3))) void*)l, 16, 0, 0);
}

// ---------------- fused prep kernel ----------------
// blocks [0,1536):        W[d][f][c] f32 -> Wt[d][c][f] bf16 (tiled transpose)
// blocks [1536,1568):     degree bucketing (LDS-aggregated histogram)
// blocks [1568,1568+8192): neighbor sum -> summed bf16 (1 wave/atom)
#define PREP_T 1536
#define PREP_B (PREP_T + 32)
#define PREP_S (PREP_B + NATOMS / 4)

__global__ __launch_bounds__(256) void prep(
    const float* __restrict__ atoms, const int* __restrict__ bonds,
    const float* __restrict__ W, __hip_bfloat16* __restrict__ Wt,
    __hip_bfloat16* __restrict__ summed, int* __restrict__ counts,
    int* __restrict__ bucket) {
    const int blk = blockIdx.x;
    const int tid = threadIdx.x;

    if (blk < PREP_T) {
        // ---- transpose W tile 32x32 ----
        __shared__ float t[32][33];
        const int tx = tid & 31, ty = tid >> 5;           // (32,8)
        const int d   = blk >> 8;
        const int rem = blk & 255;
        const int c0  = (rem & 15) * 32;
        const int f0  = (rem >> 4) * 32;
        #pragma unroll
        for (int r = 0; r < 32; r += 8)
            t[ty + r][tx] = W[((size_t)(d * NF + f0 + ty + r)) * NC + c0 + tx];
        __syncthreads();
        #pragma unroll
        for (int r = 0; r < 32; r += 8)
            Wt[((size_t)(d * NC + c0 + ty + r)) * NF + f0 + tx] =
                __float2bfloat16(t[tx][ty + r]);
    } else if (blk < PREP_B) {
        // ---- bucket atoms by degree ----
        __shared__ int lcnt[ND];
        __shared__ int lbase[ND];
        const int b = blk - PREP_T;
        if (tid < ND) lcnt[tid] = 0;
        __syncthreads();
        int deg[4], loc[4], gg[4];
        #pragma unroll
        for (int i = 0; i < 4; ++i) {
            int g = b * 1024 + i * 256 + tid;
            gg[i] = g;
            int dg = 0;
            #pragma unroll
            for (int j = 0; j < ND; ++j) dg += (bonds[g * ND + j] >= 0);
            deg[i] = dg;
            loc[i] = atomicAdd(&lcnt[dg], 1);
        }
        __syncthreads();
        if (tid < ND) lbase[tid] = atomicAdd(&counts[tid], lcnt[tid]);
        __syncthreads();
        #pragma unroll
        for (int i = 0; i < 4; ++i)
            bucket[deg[i] * NATOMS + lbase[deg[i]] + loc[i]] = gg[i];
    } else {
        // ---- neighbor gather/sum: 1 wave/atom, lane covers 8 contiguous f32 ----
        const int wave = tid >> 6;
        const int lane = tid & 63;
        const int g    = (blk - PREP_B) * 4 + wave;
        const float4* a4 = (const float4*)atoms;   // row = 128 float4

        int   nb[ND];
        float msk[ND];
        #pragma unroll
        for (int j = 0; j < ND; ++j) {
            int n = bonds[g * ND + j];
            msk[j] = (n >= 0) ? 1.0f : 0.0f;
            nb[j]  = (n >= 0) ? n : 0;
        }
        const int rowbase = g & ~(NA - 1);

        float4 s0 = a4[(size_t)g * 128 + 2 * lane];
        float4 s1 = a4[(size_t)g * 128 + 2 * lane + 1];
        float4 v0[ND], v1[ND];
        #pragma unroll
        for (int j = 0; j < ND; ++j) {
            const size_t base = (size_t)(rowbase + nb[j]) * 128 + 2 * lane;
            v0[j] = a4[base];
            v1[j] = a4[base + 1];
        }
        #pragma unroll
        for (int j = 0; j < ND; ++j) {
            s0.x = fmaf(v0[j].x, msk[j], s0.x); s0.y = fmaf(v0[j].y, msk[j], s0.y);
            s0.z = fmaf(v0[j].z, msk[j], s0.z); s0.w = fmaf(v0[j].w, msk[j], s0.w);
            s1.x = fmaf(v1[j].x, msk[j], s1.x); s1.y = fmaf(v1[j].y, msk[j], s1.y);
            s1.z = fmaf(v1[j].z, msk[j], s1.z); s1.w = fmaf(v1[j].w, msk[j], s1.w);
        }
        uint4 o;
        o.x = pack2(s0.x, s0.y); o.y = pack2(s0.z, s0.w);
        o.z = pack2(s1.x, s1.y); o.w = pack2(s1.z, s1.w);
        ((uint4*)summed)[(size_t)g * 64 + lane] = o;   // 8 bf16 at elem 8*lane
    }
}

// ---------------- gemm: per-degree gathered GEMM, dbuf BK=32 ----------------
// grid (24 = deg*col fast, 256 row-tiles slow); block 256 (4 waves, 2x2 of 64x64).
// BM=BN=128, BK=32, 16 kt iterations, double-buffered (one barrier per kt,
// stage kt+1 overlaps compute kt). LDS 2*(8+8) KB + sRows = 33 KB -> 4 blk/CU.
// Row = 64 B = 4 16B-segments; LDS (row,slot) holds global seg slot^((row>>1)&3)
// -> fragment reads are 2-way bank conflicts (free).
__global__ __launch_bounds__(256, 4) void gemm_deg(
    const __hip_bfloat16* __restrict__ summed, const __hip_bfloat16* __restrict__ Wt,
    const float* __restrict__ bias, const int* __restrict__ counts,
    const int* __restrict__ bucket, float* __restrict__ out) {
    const int bx = blockIdx.x;          // 0..23
    const int d  = bx % ND;
    const int n0 = (bx / ND) * 128;
    const int Md = counts[d];
    const int m0 = blockIdx.y * 128;
    if (m0 >= Md) return;

    __shared__ __align__(16) __hip_bfloat16 sA[2][128 * 32];
    __shared__ __align__(16) __hip_bfloat16 sB[2][128 * 32];
    __shared__ int sRows[128];

    const int tid = threadIdx.x;
    if (tid < 128) {
        int r = m0 + tid;
        sRows[tid] = (r < Md) ? bucket[d * NATOMS + r] : -1;
    }
    __syncthreads();

    const int lane = tid & 63;
    const int w    = tid >> 6;

    // staging: wave w, round c covers rows c*64 + w*16 + (lane>>2), slot lane&3
    const int slot = lane & 3;
    int   rowc[2];
    size_t gA[2];
    int   segoff[2];                    // swizzled 16B-seg byte offset in row
    #pragma unroll
    for (int c = 0; c < 2; ++c) {
        rowc[c] = c * 64 + w * 16 + (lane >> 2);
        int q = sRows[rowc[c]];
        gA[c] = (size_t)((q < 0) ? 0 : q) * (NF * 2);
        segoff[c] = (slot ^ ((rowc[c] >> 1) & 3)) * 16;
    }
    const char* smB = (const char*)summed;
    const char* wtB = (const char*)Wt + (size_t)(d * NC + n0) * (NF * 2);

    const int quad = lane >> 4, l16 = lane & 15;
    const int wy = w >> 1, wx = w & 1;

    f32x4 acc[4][4];
    #pragma unroll
    for (int i = 0; i < 4; ++i)
        #pragma unroll
        for (int j = 0; j < 4; ++j) acc[i][j] = (f32x4)0.0f;

    // precompute fragment LDS element offsets (row*32 + swizzled seg*8)
    int offA[4], offB[4];
    #pragma unroll
    for (int i = 0; i < 4; ++i) {
        const int Ra = wy * 64 + i * 16 + l16;
        offA[i] = Ra * 32 + (quad ^ ((Ra >> 1) & 3)) * 8;
        const int Rb = wx * 64 + i * 16 + l16;
        offB[i] = Rb * 32 + (quad ^ ((Rb >> 1) & 3)) * 8;
    }

    #define STAGE(kt, p)                                                         \
        {                                                                        \
            const int kb = (kt) * 64;   /* byte offset of K-slice in 1KB row */  \
            _Pragma("unroll")                                                    \
            for (int c = 0; c < 2; ++c) {                                        \
                async16(smB + gA[c] + kb + segoff[c],                            \
                        &sA[p][c * 2048 + w * 512]);                             \
                async16(wtB + (size_t)rowc[c] * (NF * 2) + kb + segoff[c],       \
                        &sB[p][c * 2048 + w * 512]);                             \
            }                                                                    \
        }

    STAGE(0, 0)
    #pragma unroll
    for (int kt = 0; kt < 16; ++kt) {
        const int p = kt & 1;
        __syncthreads();                 // buf[p] ready (vmcnt drain + barrier)
        if (kt < 15) STAGE(kt + 1, 1 - p)
        frag8 aF[4], bF[4];
        #pragma unroll
        for (int i = 0; i < 4; ++i) aF[i] = *(const frag8*)&sA[p][offA[i]];
        #pragma unroll
        for (int j = 0; j < 4; ++j) bF[j] = *(const frag8*)&sB[p][offB[j]];
        #pragma unroll
        for (int i = 0; i < 4; ++i)
            #pragma unroll
            for (int j = 0; j < 4; ++j)
                acc[i][j] = __builtin_amdgcn_mfma_f32_16x16x32_bf16(
                    aF[i], bF[j], acc[i][j], 0, 0, 0);
    }
    #undef STAGE

    // epilogue: C/D layout col = lane&15, row = quad*4 + reg; output FLOAT32
    #pragma unroll
    for (int j = 0; j < 4; ++j) {
        const int n = n0 + wx * 64 + j * 16 + l16;
        const float bv = bias[d * NC + n];
        #pragma unroll
        for (int i = 0; i < 4; ++i) {
            #pragma unroll
            for (int r = 0; r < 4; ++r) {
                const int tr = wy * 64 + i * 16 + quad * 4 + r;
                const int g  = sRows[tr];
                if (g >= 0)
                    out[(size_t)g * NC + n] = acc[i][j][r] + bv;
            }
        }
    }
}

extern "C" void kernel_launch(void* const* d_in, const int* in_sizes, int n_in,
                              void* d_out, int out_size, void* d_ws, size_t ws_size,
                              hipStream_t stream) {
    const float* atoms = (const float*)d_in[0];
    const int*   bonds = (const int*)d_in[1];
    const float* W     = (const float*)d_in[2];
    const float* bias  = (const float*)d_in[3];
    float* out = (float*)d_out;

    // workspace layout
    char* ws = (char*)d_ws;
    int* counts = (int*)ws;                                   // 6 ints (zeroed)
    int* bucket = (int*)(ws + 1024);                          // 6*32768 ints
    __hip_bfloat16* Wt     = (__hip_bfloat16*)(ws + 1024 + 786432);            // 3 MB
    __hip_bfloat16* summed = (__hip_bfloat16*)(ws + 1024 + 786432 + 3145728);  // 32 MB

    hipMemsetAsync(counts, 0, 1024, stream);

    prep<<<PREP_S, 256, 0, stream>>>(atoms, bonds, W, Wt, summed, counts, bucket);

    gemm_deg<<<dim3(24, NATOMS / 128), 256, 0, stream>>>(
        summed, Wt, bias, counts, bucket, out);
}